// Round 9
// baseline (228.314 us; speedup 1.0000x reference)
//
#include <hip/hip_runtime.h>

// D=128, S=64, K=32 structural. R, V, B, L from in_sizes.
// Workspace layout:
//   Wpk  : 40 KB   fragment-ordered bf16 weight image for kA ([Mw|Ww] cols 0..159)
//   Z    : V*128 B WM[v,:] = (word_emb @ M_w)[v,:] as 128 fp8 e4m3, scaled x64
//   WW8  : V*32 B  WW[v,:] = (word_emb @ W_w)[v,:] as  32 fp8 e4m3, scaled x64
//   pbuf : R*128 B aspect probs p_t [R,32] f32
// M_b dropped: softmax-invariant (exact). T_w/T_b deferred to k4: mean(p)@Tw+Tb (exact).

typedef __attribute__((ext_vector_type(8))) short bf16x8;   // 8 bf16 (4 VGPRs)
typedef __attribute__((ext_vector_type(4))) float f32x4;
typedef __attribute__((ext_vector_type(2))) float vf2;

__device__ __forceinline__ unsigned int f2bf_rne(float x) {
  unsigned int u = __float_as_uint(x);
  return (u + 0x7fffu + ((u >> 16) & 1u)) >> 16;  // round-to-nearest-even
}

// ---------------- kA0: one-shot scatter of weights into fragment-chunk order.
__global__ __launch_bounds__(256) void kA0_pack(
    const float* __restrict__ Mw, const float* __restrict__ Ww,
    uint4* __restrict__ Wpk) {
  int c = blockIdx.x * 256 + threadIdx.x;
  if (c >= 2560) return;
  int cl = c & 63, g = c >> 6;
  int jt = g >> 2, ks = g & 3;
  int n = jt * 16 + (cl & 15);
  int k0 = ks * 32 + (cl >> 4) * 8;
  float v[8];
#pragma unroll
  for (int j = 0; j < 8; ++j) {
    int e = k0 + j;
    v[j] = (n < 128) ? Mw[(size_t)e * 128 + n] : Ww[(size_t)e * 32 + (n - 128)];
  }
  uint4 pk;
  pk.x = f2bf_rne(v[0]) | (f2bf_rne(v[1]) << 16);
  pk.y = f2bf_rne(v[2]) | (f2bf_rne(v[3]) << 16);
  pk.z = f2bf_rne(v[4]) | (f2bf_rne(v[5]) << 16);
  pk.w = f2bf_rne(v[6]) | (f2bf_rne(v[7]) << 16);
  Wpk[c] = pk;
}

// ---------------- kA: [Z | WW8] = fp8(We @ [Mw|Ww] * 64) via MFMA. 64 rows/block.
__global__ __launch_bounds__(256, 2) void kA_mfma(
    const float* __restrict__ We, const uint4* __restrict__ Wpk,
    unsigned char* __restrict__ Z, unsigned char* __restrict__ WW8, int V) {
  __shared__ uint4 Bs[2560];  // 40 KB
  int t = threadIdx.x;
  int L = t & 63, wid = t >> 6;

#pragma unroll
  for (int q = 0; q < 10; ++q) Bs[t + q * 256] = Wpk[t + q * 256];

  int r0 = blockIdx.x * 64;
  if (r0 > V - 64) r0 = V - 64;          // overlap-duplicate: identical writes, benign
  int rowA = r0 + wid * 16 + (L & 15);   // A-frag row: m = lane&15
  const float4* Arow = (const float4*)(We + (size_t)rowA * 128);

  float4 a[8];
#pragma unroll
  for (int ks = 0; ks < 4; ++ks) {
    int koff4 = ks * 8 + (L >> 4) * 2;
    a[ks * 2] = Arow[koff4];
    a[ks * 2 + 1] = Arow[koff4 + 1];
  }
  union { uint4 u; bf16x8 v; } A[4];
#pragma unroll
  for (int ks = 0; ks < 4; ++ks) {
    A[ks].u.x = f2bf_rne(a[ks * 2].x) | (f2bf_rne(a[ks * 2].y) << 16);
    A[ks].u.y = f2bf_rne(a[ks * 2].z) | (f2bf_rne(a[ks * 2].w) << 16);
    A[ks].u.z = f2bf_rne(a[ks * 2 + 1].x) | (f2bf_rne(a[ks * 2 + 1].y) << 16);
    A[ks].u.w = f2bf_rne(a[ks * 2 + 1].z) | (f2bf_rne(a[ks * 2 + 1].w) << 16);
  }
  __syncthreads();

  f32x4 acc[10];
#pragma unroll
  for (int jt = 0; jt < 10; ++jt) acc[jt] = (f32x4){0.f, 0.f, 0.f, 0.f};
#pragma unroll
  for (int ks = 0; ks < 4; ++ks) {
#pragma unroll
    for (int jt = 0; jt < 10; ++jt) {
      union { uint4 u; bf16x8 v; } Bf;
      Bf.u = Bs[(jt * 4 + ks) * 64 + L];
      acc[jt] = __builtin_amdgcn_mfma_f32_16x16x32_bf16(A[ks].v, Bf.v, acc[jt], 0, 0, 0);
    }
  }

#pragma unroll
  for (int jt = 0; jt < 10; ++jt) {
#pragma unroll
    for (int i = 0; i < 4; ++i) {
      float v0 = acc[jt][i] * 64.f;
      float v1 = __shfl_xor(v0, 1);
      float v2 = __shfl_xor(v0, 2);
      float v3 = __shfl_xor(v0, 3);
      if (!(L & 3)) {
        int col = jt * 16 + (L & 15);
        int orow = r0 + wid * 16 + (L >> 4) * 4 + i;
        int w8 = __builtin_amdgcn_cvt_pk_fp8_f32(v0, v1, 0, false);
        w8 = __builtin_amdgcn_cvt_pk_fp8_f32(v2, v3, w8, true);
        if (col < 128)
          *(int*)(Z + (size_t)orow * 128 + col) = w8;
        else
          *(int*)(WW8 + (size_t)orow * 32 + (col - 128)) = w8;
      }
    }
  }
}

__device__ __forceinline__ float dot_fp8_16_pk(uint4 q, const float4* y) {
  vf2 acc = {0.f, 0.f};
#pragma unroll
  for (int i = 0; i < 4; ++i) {
    unsigned int u = (&q.x)[i];
    vf2 a = __builtin_amdgcn_cvt_pk_f32_fp8(u, false);  // bytes 0,1
    vf2 b = __builtin_amdgcn_cvt_pk_f32_fp8(u, true);   // bytes 2,3
    float4 yv = y[i];
    vf2 ylo = {yv.x, yv.y}, yhi = {yv.z, yv.w};
    acc += a * ylo;   // v_pk_fma_f32
    acc += b * yhi;
  }
  return acc.x + acc.y;
}

// ---------------- k3: attention + aspect probs. FOUR reviews per wave; all 48
// random gathers structurally live before any compute (forces real MLP).
__global__ __launch_bounds__(256, 2) void k3_review(
    const int* __restrict__ hr, const float* __restrict__ Y,
    const unsigned char* __restrict__ Z, const unsigned char* __restrict__ WW8,
    const float* __restrict__ Wb, float* __restrict__ pOut, int R) {
  int t = threadIdx.x;
  int wv = t >> 6, lane = t & 63;
  int g = lane & 15, sub = lane >> 4;
  int rbase = (blockIdx.x * 4 + wv) * 4;
  int rr[4];
#pragma unroll
  for (int v = 0; v < 4; ++v) {
    int r = rbase + v;
    rr[v] = r < R ? r : R - 1;           // tail duplicates: identical writes, benign
  }

  int word[4];
#pragma unroll
  for (int v = 0; v < 4; ++v) word[v] = hr[(size_t)rr[v] * 64 + lane];

  // ---- issue ALL random gathers for all four reviews up-front (48 in flight)
  uint4 q0[4][4], q1[4][4];
  uint2 w8[4][4];
#pragma unroll
  for (int p = 0; p < 4; ++p) {
#pragma unroll
    for (int v = 0; v < 4; ++v) {
      int w = __shfl(word[v], p * 16 + g);
      const unsigned char* b = Z + (size_t)w * 128;
      q0[v][p] = *(const uint4*)(b + sub * 16);
      q1[v][p] = *(const uint4*)(b + 64 + sub * 16);
      w8[v][p] = *(const uint2*)(WW8 + (size_t)w * 32 + sub * 8);
    }
  }
  const float4* Wb4 = (const float4*)Wb;
  float4 wba = Wb4[sub * 2], wbb = Wb4[sub * 2 + 1];

  // y double-buffer across the review loop
  float4 ya[2][4], yb[2][4];
  {
    const float4* Y0 = (const float4*)(Y + (size_t)rr[0] * 128);
#pragma unroll
    for (int i = 0; i < 4; ++i) { ya[0][i] = Y0[sub * 4 + i]; yb[0][i] = Y0[16 + sub * 4 + i]; }
  }

#pragma unroll
  for (int v = 0; v < 4; ++v) {
    int cur = v & 1, nxt = cur ^ 1;
    if (v < 3) {
      const float4* Yn = (const float4*)(Y + (size_t)rr[v + 1] * 128);
#pragma unroll
      for (int i = 0; i < 4; ++i) { ya[nxt][i] = Yn[sub * 4 + i]; yb[nxt][i] = Yn[16 + sub * 4 + i]; }
    }

    // ---- dx: 4 lanes per word, reduce over sub groups
    float dxp[4];
#pragma unroll
    for (int p = 0; p < 4; ++p) {
      float acc = dot_fp8_16_pk(q0[v][p], ya[cur]) + dot_fp8_16_pk(q1[v][p], yb[cur]);
      acc += __shfl_xor(acc, 16);
      acc += __shfl_xor(acc, 32);
      dxp[p] = acc * 0.015625f;  // undo x64 fp8 scale
    }
    float dx = dxp[0];
    dx = (sub == 1) ? dxp[1] : dx;
    dx = (sub == 2) ? dxp[2] : dx;
    dx = (sub == 3) ? dxp[3] : dx;

    // ---- softmax over 64 words (wave-wide)
    float m = dx;
#pragma unroll
    for (int off = 32; off; off >>= 1) m = fmaxf(m, __shfl_xor(m, off));
    float ex = __expf(dx - m);
    float sum = ex;
#pragma unroll
    for (int off = 32; off; off >>= 1) sum += __shfl_xor(sum, off);
    float ax = ex / sum;                 // lane holds ax for word s = lane

    // ---- logits: lane accumulates k = sub*8+j over its 4 words (packed f32)
    vf2 lacc2[4];
#pragma unroll
    for (int j = 0; j < 4; ++j) lacc2[j] = (vf2){0.f, 0.f};
#pragma unroll
    for (int p = 0; p < 4; ++p) {
      float axp = __shfl(ax, p * 16 + g);
      vf2 ax2 = {axp, axp};
      lacc2[0] += ax2 * __builtin_amdgcn_cvt_pk_f32_fp8(w8[v][p].x, false);
      lacc2[1] += ax2 * __builtin_amdgcn_cvt_pk_f32_fp8(w8[v][p].x, true);
      lacc2[2] += ax2 * __builtin_amdgcn_cvt_pk_f32_fp8(w8[v][p].y, false);
      lacc2[3] += ax2 * __builtin_amdgcn_cvt_pk_f32_fp8(w8[v][p].y, true);
    }
    float lacc[8];
#pragma unroll
    for (int j = 0; j < 4; ++j) { lacc[j * 2] = lacc2[j].x; lacc[j * 2 + 1] = lacc2[j].y; }
#pragma unroll
    for (int off = 8; off; off >>= 1) {
#pragma unroll
      for (int j = 0; j < 8; ++j) lacc[j] += __shfl_xor(lacc[j], off);
    }
    lacc[0] = lacc[0] * 0.015625f + wba.x; lacc[1] = lacc[1] * 0.015625f + wba.y;
    lacc[2] = lacc[2] * 0.015625f + wba.z; lacc[3] = lacc[3] * 0.015625f + wba.w;
    lacc[4] = lacc[4] * 0.015625f + wbb.x; lacc[5] = lacc[5] * 0.015625f + wbb.y;
    lacc[6] = lacc[6] * 0.015625f + wbb.z; lacc[7] = lacc[7] * 0.015625f + wbb.w;

    // ---- softmax over K=32 (8 regs/lane x 4 sub groups)
    float mk = lacc[0];
#pragma unroll
    for (int j = 1; j < 8; ++j) mk = fmaxf(mk, lacc[j]);
    mk = fmaxf(mk, __shfl_xor(mk, 16));
    mk = fmaxf(mk, __shfl_xor(mk, 32));
    float ek[8], sk = 0.f;
#pragma unroll
    for (int j = 0; j < 8; ++j) { ek[j] = __expf(lacc[j] - mk); sk += ek[j]; }
    sk += __shfl_xor(sk, 16);
    sk += __shfl_xor(sk, 32);
    float inv = 1.0f / sk;

    if (g == 0) {
      float4 o0, o1;
      o0.x = ek[0] * inv; o0.y = ek[1] * inv; o0.z = ek[2] * inv; o0.w = ek[3] * inv;
      o1.x = ek[4] * inv; o1.y = ek[5] * inv; o1.z = ek[6] * inv; o1.w = ek[7] * inv;
      float* dst = pOut + (size_t)rr[v] * 32 + sub * 8;
      *(float4*)dst = o0;
      *(float4*)(dst + 4) = o1;
    }
  }
}

// ---------------- k4: pool p over contiguous segments, apply Tw/Tb, final dot.
__global__ __launch_bounds__(256) void k4_final(
    const float* __restrict__ p, const int* __restrict__ uidx,
    const int* __restrict__ iidx, const int* __restrict__ user,
    const int* __restrict__ item, const float* __restrict__ uemb,
    const float* __restrict__ iemb, const float* __restrict__ Tw,
    const float* __restrict__ Tb, const float* __restrict__ avg,
    float* __restrict__ out, int B, int per) {
  int t = threadIdx.x;
  int w = t >> 6, lane = t & 63;
  int b = blockIdx.x * 4 + w;
  if (b >= B) return;

  int k = lane & 31;
  const int* idx = (lane < 32) ? uidx : iidx;
  float pbar = 0.f;
  int base = b * per;
  for (int j = 0; j < per; ++j) {
    int id = idx[base + j];
    pbar += p[(size_t)id * 32 + k];
  }
  pbar *= 1.0f / (float)per;

  const float2* T2 = (const float2*)Tw;
  float2 tb2 = ((const float2*)Tb)[lane];
  float2 ua = tb2, ia = tb2;
#pragma unroll 8
  for (int kk = 0; kk < 32; ++kk) {
    float pu = __shfl(pbar, kk);
    float pi = __shfl(pbar, 32 + kk);
    float2 tv = T2[kk * 64 + lane];
    ua.x += pu * tv.x; ua.y += pu * tv.y;
    ia.x += pi * tv.x; ia.y += pi * tv.y;
  }
  float part = ua.x * ia.x + ua.y * ia.y;
  float2 uf = ((const float2*)uemb)[(size_t)user[b] * 64 + lane];
  float2 itf = ((const float2*)iemb)[(size_t)item[b] * 64 + lane];
  part += uf.x * itf.x + uf.y * itf.y;
#pragma unroll
  for (int off = 32; off; off >>= 1) part += __shfl_xor(part, off);
  if (lane == 0) out[b] = part + avg[0];
}

extern "C" void kernel_launch(void* const* d_in, const int* in_sizes, int n_in,
                              void* d_out, int out_size, void* d_ws, size_t ws_size,
                              hipStream_t stream) {
  const int*   user = (const int*)d_in[0];
  const int*   item = (const int*)d_in[1];
  const int*   hr   = (const int*)d_in[2];
  const float* Y    = (const float*)d_in[3];   // [R,128]
  const int*   uhi  = (const int*)d_in[4];
  const int*   ihi  = (const int*)d_in[6];
  const float* We   = (const float*)d_in[8];   // [V,128]
  const float* Mw   = (const float*)d_in[9];   // [128,128]
  // d_in[10]: M_b — softmax-invariant, dropped
  const float* Ww   = (const float*)d_in[11];  // [128,32]
  const float* Wb   = (const float*)d_in[12];  // [32]
  const float* Tw   = (const float*)d_in[13];  // [32,128]
  const float* Tb   = (const float*)d_in[14];  // [128]
  const float* Ue   = (const float*)d_in[15];
  const float* Ie   = (const float*)d_in[16];
  const float* avg  = (const float*)d_in[17];

  int B = in_sizes[0];
  int R = in_sizes[3] / 128;
  int V = in_sizes[8] / 128;
  int L = in_sizes[4];
  int per = L / B;

  unsigned char* ws = (unsigned char*)d_ws;
  uint4* Wpk = (uint4*)ws;                               // 40 KB
  unsigned char* Z   = ws + 40960;                       // V*128
  unsigned char* WW8 = Z + (size_t)V * 128;              // V*32
  float* pbuf = (float*)(WW8 + (size_t)V * 32);          // R*32 floats
  float* out = (float*)d_out;

  kA0_pack<<<10, 256, 0, stream>>>(Mw, Ww, Wpk);
  kA_mfma<<<(V + 63) / 64, 256, 0, stream>>>(We, Wpk, Z, WW8, V);
  k3_review<<<(R + 15) / 16, 256, 0, stream>>>(hr, Y, Z, WW8, Wb, pbuf, R);
  k4_final<<<(B + 3) / 4, 256, 0, stream>>>(pbuf, uhi, ihi, user, item, Ue, Ie,
                                            Tw, Tb, avg, out, B, per);
}

// Round 10
// 222.107 us; speedup vs baseline: 1.0279x; 1.0279x over previous
//
#include <hip/hip_runtime.h>

// D=128, S=64, K=32 structural. R, V, B, L from in_sizes.
// PERMUTED table layout (exact — dot products are permutation-invariant):
//   Z row (128 B):  byte pos = c*8 + jt  holds fp8(WM[v, d=jt*16+c] * 64),  c<16, jt<8
//   WW8 row (32 B): byte pos = c*2 + j   holds fp8(WW[v, k=j*16+c] * 64),   c<16, j<2
//   Yp[r,pos] = Y[r, (pos&7)*16 + (pos>>3)]  (so Z byte pos pairs with Yp float pos)
//   pOut[r, sub*8+b] = p[r, k=(b&1)*16+4*sub+(b>>1)]  (k4 maps back via Tw row index)
// M_b dropped: softmax-invariant (exact). T_w/T_b deferred to k4 (exact).

typedef __attribute__((ext_vector_type(8))) short bf16x8;   // 8 bf16 (4 VGPRs)
typedef __attribute__((ext_vector_type(4))) float f32x4;
typedef __attribute__((ext_vector_type(2))) float vf2;

__device__ __forceinline__ unsigned int f2bf_rne(float x) {
  unsigned int u = __float_as_uint(x);
  return (u + 0x7fffu + ((u >> 16) & 1u)) >> 16;  // round-to-nearest-even
}

// ---------------- kA0: one-shot scatter of weights into MFMA fragment-chunk order.
__global__ __launch_bounds__(256) void kA0_pack(
    const float* __restrict__ Mw, const float* __restrict__ Ww,
    uint4* __restrict__ Wpk) {
  int c = blockIdx.x * 256 + threadIdx.x;
  if (c >= 2560) return;
  int cl = c & 63, g = c >> 6;
  int jt = g >> 2, ks = g & 3;
  int n = jt * 16 + (cl & 15);
  int k0 = ks * 32 + (cl >> 4) * 8;
  float v[8];
#pragma unroll
  for (int j = 0; j < 8; ++j) {
    int e = k0 + j;
    v[j] = (n < 128) ? Mw[(size_t)e * 128 + n] : Ww[(size_t)e * 32 + (n - 128)];
  }
  uint4 pk;
  pk.x = f2bf_rne(v[0]) | (f2bf_rne(v[1]) << 16);
  pk.y = f2bf_rne(v[2]) | (f2bf_rne(v[3]) << 16);
  pk.z = f2bf_rne(v[4]) | (f2bf_rne(v[5]) << 16);
  pk.w = f2bf_rne(v[6]) | (f2bf_rne(v[7]) << 16);
  Wpk[c] = pk;
}

// ---------------- kY: permute Y rows into Yp (exact copy, reordered).
__global__ __launch_bounds__(256) void kY_perm(
    const float* __restrict__ Y, float* __restrict__ Yp, int n) {
  int i = blockIdx.x * 256 + threadIdx.x;
  if (i >= n) return;
  int r = i >> 7, pos = i & 127;
  int d = ((pos & 7) << 4) + (pos >> 3);
  Yp[i] = Y[(size_t)(r << 7) + d];
}

// ---------------- kA: [Z | WW8] = fp8(We @ [Mw|Ww] * 64) via MFMA, permuted stores.
__global__ __launch_bounds__(256, 2) void kA_mfma(
    const float* __restrict__ We, const uint4* __restrict__ Wpk,
    unsigned char* __restrict__ Z, unsigned char* __restrict__ WW8, int V) {
  __shared__ uint4 Bs[2560];  // 40 KB
  int t = threadIdx.x;
  int L = t & 63, wid = t >> 6;

#pragma unroll
  for (int q = 0; q < 10; ++q) Bs[t + q * 256] = Wpk[t + q * 256];

  int r0 = blockIdx.x * 64;
  if (r0 > V - 64) r0 = V - 64;          // overlap-duplicate: identical writes, benign
  int rowA = r0 + wid * 16 + (L & 15);   // A-frag row: m = lane&15
  const float4* Arow = (const float4*)(We + (size_t)rowA * 128);

  float4 a[8];
#pragma unroll
  for (int ks = 0; ks < 4; ++ks) {
    int koff4 = ks * 8 + (L >> 4) * 2;
    a[ks * 2] = Arow[koff4];
    a[ks * 2 + 1] = Arow[koff4 + 1];
  }
  union { uint4 u; bf16x8 v; } A[4];
#pragma unroll
  for (int ks = 0; ks < 4; ++ks) {
    A[ks].u.x = f2bf_rne(a[ks * 2].x) | (f2bf_rne(a[ks * 2].y) << 16);
    A[ks].u.y = f2bf_rne(a[ks * 2].z) | (f2bf_rne(a[ks * 2].w) << 16);
    A[ks].u.z = f2bf_rne(a[ks * 2 + 1].x) | (f2bf_rne(a[ks * 2 + 1].y) << 16);
    A[ks].u.w = f2bf_rne(a[ks * 2 + 1].z) | (f2bf_rne(a[ks * 2 + 1].w) << 16);
  }
  __syncthreads();

  f32x4 acc[10];
#pragma unroll
  for (int jt = 0; jt < 10; ++jt) acc[jt] = (f32x4){0.f, 0.f, 0.f, 0.f};
#pragma unroll
  for (int ks = 0; ks < 4; ++ks) {
#pragma unroll
    for (int jt = 0; jt < 10; ++jt) {
      union { uint4 u; bf16x8 v; } Bf;
      Bf.u = Bs[(jt * 4 + ks) * 64 + L];
      acc[jt] = __builtin_amdgcn_mfma_f32_16x16x32_bf16(A[ks].v, Bf.v, acc[jt], 0, 0, 0);
    }
  }

  // ---- permuted epilogue: lane (c = L&15, q = L>>4) owns bytes c*8..c*8+7 of
  // rows q*4+i. All-lane coalesced uint2 stores, zero shfls.
  int c = L & 15, q = L >> 4;
#pragma unroll
  for (int i = 0; i < 4; ++i) {
    int orow = r0 + wid * 16 + q * 4 + i;
    int dwA = __builtin_amdgcn_cvt_pk_fp8_f32(acc[0][i] * 64.f, acc[1][i] * 64.f, 0, false);
    dwA = __builtin_amdgcn_cvt_pk_fp8_f32(acc[2][i] * 64.f, acc[3][i] * 64.f, dwA, true);
    int dwB = __builtin_amdgcn_cvt_pk_fp8_f32(acc[4][i] * 64.f, acc[5][i] * 64.f, 0, false);
    dwB = __builtin_amdgcn_cvt_pk_fp8_f32(acc[6][i] * 64.f, acc[7][i] * 64.f, dwB, true);
    uint2 st; st.x = (unsigned int)dwA; st.y = (unsigned int)dwB;
    *(uint2*)(Z + (size_t)orow * 128 + c * 8) = st;
    int dwC = __builtin_amdgcn_cvt_pk_fp8_f32(acc[8][i] * 64.f, acc[9][i] * 64.f, 0, false);
    *(unsigned short*)(WW8 + (size_t)orow * 32 + c * 2) = (unsigned short)dwC;
  }
}

// dot of 16 fp8 bytes (dwords of q) against 8 consecutive float2 of y2.
__device__ __forceinline__ vf2 dot_fp8_16_pk(uint4 q, const vf2* y2, vf2 acc) {
#pragma unroll
  for (int w = 0; w < 4; ++w) {
    unsigned int u = (&q.x)[w];
    acc += __builtin_amdgcn_cvt_pk_f32_fp8(u, false) * y2[2 * w];
    acc += __builtin_amdgcn_cvt_pk_f32_fp8(u, true) * y2[2 * w + 1];
  }
  return acc;
}

// ---------------- k3: attention + aspect probs. TWO reviews per wave (R8 structure),
// permuted Z/WW8/Yp layouts. Barrier-free.
__global__ __launch_bounds__(256, 2) void k3_review(
    const int* __restrict__ hr, const float* __restrict__ Yp,
    const unsigned char* __restrict__ Z, const unsigned char* __restrict__ WW8,
    const float* __restrict__ Wb, float* __restrict__ pOut, int R) {
  int t = threadIdx.x;
  int wv = t >> 6, lane = t & 63;
  int g = lane & 15, sub = lane >> 4;
  int rbase = (blockIdx.x * 4 + wv) * 2;
  int r0 = rbase < R ? rbase : R - 1;
  int r1 = rbase + 1 < R ? rbase + 1 : R - 1;

  int word0 = hr[(size_t)r0 * 64 + lane];
  int word1 = hr[(size_t)r1 * 64 + lane];

  // ---- issue ALL random gathers for both reviews up-front
  uint4 q0[2][4], q1[2][4];
  uint2 w8[2][4];
#pragma unroll
  for (int p = 0; p < 4; ++p) {
    int wa = __shfl(word0, p * 16 + g);
    int wb = __shfl(word1, p * 16 + g);
    const unsigned char* ba = Z + (size_t)wa * 128 + sub * 32;
    const unsigned char* bb = Z + (size_t)wb * 128 + sub * 32;
    q0[0][p] = *(const uint4*)(ba);
    q1[0][p] = *(const uint4*)(ba + 16);
    w8[0][p] = *(const uint2*)(WW8 + (size_t)wa * 32 + sub * 8);
    q0[1][p] = *(const uint4*)(bb);
    q1[1][p] = *(const uint4*)(bb + 16);
    w8[1][p] = *(const uint2*)(WW8 + (size_t)wb * 32 + sub * 8);
  }
  // Yp fragments: lane needs floats pos = sub*32 .. sub*32+31 (contiguous)
  float4 yv[2][8];
#pragma unroll
  for (int i = 0; i < 8; ++i) {
    yv[0][i] = ((const float4*)(Yp + (size_t)r0 * 128))[sub * 8 + i];
    yv[1][i] = ((const float4*)(Yp + (size_t)r1 * 128))[sub * 8 + i];
  }
  const float4* Wb4 = (const float4*)Wb;
  float4 wbe = Wb4[sub];      // k = 4sub+m   -> lacc[2m]
  float4 wbo = Wb4[4 + sub];  // k = 16+4sub+m -> lacc[2m+1]

#pragma unroll
  for (int v = 0; v < 2; ++v) {
    int r = v ? r1 : r0;
    const vf2* y2 = (const vf2*)yv[v];  // 16 float2

    // ---- dx: 4 lanes per word, reduce over sub groups
    float dxp[4];
#pragma unroll
    for (int p = 0; p < 4; ++p) {
      vf2 a2 = {0.f, 0.f};
      a2 = dot_fp8_16_pk(q0[v][p], y2, a2);
      a2 = dot_fp8_16_pk(q1[v][p], y2 + 8, a2);
      float acc = a2.x + a2.y;
      acc += __shfl_xor(acc, 16);
      acc += __shfl_xor(acc, 32);
      dxp[p] = acc * 0.015625f;  // undo x64 fp8 scale
    }
    float dx = dxp[0];
    dx = (sub == 1) ? dxp[1] : dx;
    dx = (sub == 2) ? dxp[2] : dx;
    dx = (sub == 3) ? dxp[3] : dx;

    // ---- softmax over 64 words (wave-wide)
    float m = dx;
#pragma unroll
    for (int off = 32; off; off >>= 1) m = fmaxf(m, __shfl_xor(m, off));
    float ex = __expf(dx - m);
    float sum = ex;
#pragma unroll
    for (int off = 32; off; off >>= 1) sum += __shfl_xor(sum, off);
    float ax = ex / sum;                 // lane holds ax for word s = lane

    // ---- logits: lacc[b] ~ aspect k=(b&1)*16+4sub+(b>>1); accumulate over 4 words
    float lacc[8];
#pragma unroll
    for (int j = 0; j < 8; ++j) lacc[j] = 0.f;
#pragma unroll
    for (int p = 0; p < 4; ++p) {
      float axp = __shfl(ax, p * 16 + g);
      vf2 a0 = __builtin_amdgcn_cvt_pk_f32_fp8(w8[v][p].x, false);
      vf2 a1 = __builtin_amdgcn_cvt_pk_f32_fp8(w8[v][p].x, true);
      vf2 a2 = __builtin_amdgcn_cvt_pk_f32_fp8(w8[v][p].y, false);
      vf2 a3 = __builtin_amdgcn_cvt_pk_f32_fp8(w8[v][p].y, true);
      lacc[0] += axp * a0.x; lacc[1] += axp * a0.y;
      lacc[2] += axp * a1.x; lacc[3] += axp * a1.y;
      lacc[4] += axp * a2.x; lacc[5] += axp * a2.y;
      lacc[6] += axp * a3.x; lacc[7] += axp * a3.y;
    }
#pragma unroll
    for (int off = 8; off; off >>= 1) {
#pragma unroll
      for (int j = 0; j < 8; ++j) lacc[j] += __shfl_xor(lacc[j], off);
    }
    lacc[0] = lacc[0] * 0.015625f + wbe.x; lacc[1] = lacc[1] * 0.015625f + wbo.x;
    lacc[2] = lacc[2] * 0.015625f + wbe.y; lacc[3] = lacc[3] * 0.015625f + wbo.y;
    lacc[4] = lacc[4] * 0.015625f + wbe.z; lacc[5] = lacc[5] * 0.015625f + wbo.z;
    lacc[6] = lacc[6] * 0.015625f + wbe.w; lacc[7] = lacc[7] * 0.015625f + wbo.w;

    // ---- softmax over K=32 (mapping-invariant)
    float mk = lacc[0];
#pragma unroll
    for (int j = 1; j < 8; ++j) mk = fmaxf(mk, lacc[j]);
    mk = fmaxf(mk, __shfl_xor(mk, 16));
    mk = fmaxf(mk, __shfl_xor(mk, 32));
    float ek[8], sk = 0.f;
#pragma unroll
    for (int j = 0; j < 8; ++j) { ek[j] = __expf(lacc[j] - mk); sk += ek[j]; }
    sk += __shfl_xor(sk, 16);
    sk += __shfl_xor(sk, 32);
    float inv = 1.0f / sk;

    // ---- write p in permuted order at positions sub*8 + b
    if (g == 0) {
      float4 o0, o1;
      o0.x = ek[0] * inv; o0.y = ek[1] * inv; o0.z = ek[2] * inv; o0.w = ek[3] * inv;
      o1.x = ek[4] * inv; o1.y = ek[5] * inv; o1.z = ek[6] * inv; o1.w = ek[7] * inv;
      float* dst = pOut + (size_t)r * 32 + sub * 8;
      *(float4*)dst = o0;
      *(float4*)(dst + 4) = o1;
    }
  }
}

// ---------------- k4: pool permuted p over contiguous segments, apply Tw/Tb, dot.
__global__ __launch_bounds__(256) void k4_final(
    const float* __restrict__ p, const int* __restrict__ uidx,
    const int* __restrict__ iidx, const int* __restrict__ user,
    const int* __restrict__ item, const float* __restrict__ uemb,
    const float* __restrict__ iemb, const float* __restrict__ Tw,
    const float* __restrict__ Tb, const float* __restrict__ avg,
    float* __restrict__ out, int B, int per) {
  int t = threadIdx.x;
  int w = t >> 6, lane = t & 63;
  int b = blockIdx.x * 4 + w;
  if (b >= B) return;

  int idx = lane & 31;  // permuted p position
  const int* sidx = (lane < 32) ? uidx : iidx;
  float pbar = 0.f;
  int base = b * per;
  for (int j = 0; j < per; ++j) {
    int id = sidx[base + j];
    pbar += p[(size_t)id * 32 + idx];
  }
  pbar *= 1.0f / (float)per;

  const float2* T2 = (const float2*)Tw;
  float2 tb2 = ((const float2*)Tb)[lane];
  float2 ua = tb2, ia = tb2;
#pragma unroll 8
  for (int kk = 0; kk < 32; ++kk) {
    int ka = ((kk & 1) << 4) + ((kk >> 3) << 2) + ((kk & 7) >> 1);  // aspect of pos kk
    float pu = __shfl(pbar, kk);
    float pi = __shfl(pbar, 32 + kk);
    float2 tv = T2[ka * 64 + lane];
    ua.x += pu * tv.x; ua.y += pu * tv.y;
    ia.x += pi * tv.x; ia.y += pi * tv.y;
  }
  float part = ua.x * ia.x + ua.y * ia.y;
  float2 uf = ((const float2*)uemb)[(size_t)user[b] * 64 + lane];
  float2 itf = ((const float2*)iemb)[(size_t)item[b] * 64 + lane];
  part += uf.x * itf.x + uf.y * itf.y;
#pragma unroll
  for (int off = 32; off; off >>= 1) part += __shfl_xor(part, off);
  if (lane == 0) out[b] = part + avg[0];
}

extern "C" void kernel_launch(void* const* d_in, const int* in_sizes, int n_in,
                              void* d_out, int out_size, void* d_ws, size_t ws_size,
                              hipStream_t stream) {
  const int*   user = (const int*)d_in[0];
  const int*   item = (const int*)d_in[1];
  const int*   hr   = (const int*)d_in[2];
  const float* Y    = (const float*)d_in[3];   // [R,128]
  const int*   uhi  = (const int*)d_in[4];
  const int*   ihi  = (const int*)d_in[6];
  const float* We   = (const float*)d_in[8];   // [V,128]
  const float* Mw   = (const float*)d_in[9];   // [128,128]
  // d_in[10]: M_b — softmax-invariant, dropped
  const float* Ww   = (const float*)d_in[11];  // [128,32]
  const float* Wb   = (const float*)d_in[12];  // [32]
  const float* Tw   = (const float*)d_in[13];  // [32,128]
  const float* Tb   = (const float*)d_in[14];  // [128]
  const float* Ue   = (const float*)d_in[15];
  const float* Ie   = (const float*)d_in[16];
  const float* avg  = (const float*)d_in[17];

  int B = in_sizes[0];
  int R = in_sizes[3] / 128;
  int V = in_sizes[8] / 128;
  int L = in_sizes[4];
  int per = L / B;

  unsigned char* ws = (unsigned char*)d_ws;
  uint4* Wpk = (uint4*)ws;                               // 40 KB
  unsigned char* Z   = ws + 40960;                       // V*128
  unsigned char* WW8 = Z + (size_t)V * 128;              // V*32
  float* Yp   = (float*)(WW8 + (size_t)V * 32);          // R*128 floats
  float* pbuf = Yp + (size_t)R * 128;                    // R*32 floats
  float* out = (float*)d_out;

  kA0_pack<<<10, 256, 0, stream>>>(Mw, Ww, Wpk);
  kY_perm<<<(R * 128 + 255) / 256, 256, 0, stream>>>(Y, Yp, R * 128);
  kA_mfma<<<(V + 63) / 64, 256, 0, stream>>>(We, Wpk, Z, WW8, V);
  k3_review<<<(R + 7) / 8, 256, 0, stream>>>(hr, Yp, Z, WW8, Wb, pbuf, R);
  k4_final<<<(B + 3) / 4, 256, 0, stream>>>(pbuf, uhi, ihi, user, item, Ue, Ie,
                                            Tw, Tb, avg, out, B, per);
}